// Round 1
// baseline (886.631 us; speedup 1.0000x reference)
//
#include <hip/hip_runtime.h>

#define BB   64
#define CC   2208
#define NN   196
#define KK   200
#define EPSF 1e-12f

// ---------------------------------------------------------------------------
// Kernel A: scores[b][n][k] = sum_c x[b,c,n] * w[k,c]   (bias added later)
// grid = 512 blocks: bid = (b<<3) | (nq<<1) | kh
//   b  = batch, nq = position quarter (49 positions), kh = class half (100)
// block = 256 threads: tp = t&63 (position lane, 49 valid), tk = t>>6 (0..3)
// each thread: 1 position x 25 classes, acc[25] in VGPRs
// x tile staged in LDS; w read at wave-uniform addresses -> SGPR (s_load)
// ---------------------------------------------------------------------------
__global__ __launch_bounds__(256) void scores_kernel(
    const float* __restrict__ x, const float* __restrict__ w,
    float* __restrict__ scores)
{
    const int bid = blockIdx.x;
    const int b   = bid >> 3;
    const int nq  = (bid >> 1) & 3;
    const int kh  = bid & 1;
    const int t   = threadIdx.x;
    const int tp  = t & 63;
    const int tk  = t >> 6;                       // wave-uniform (wave = 64)
    const int tku = __builtin_amdgcn_readfirstlane(tk);
    const int kbase = kh * 100 + tku * 25;
    const float* __restrict__ wb = w + (size_t)kbase * CC;
    const int nbase = nq * 49;

    __shared__ float xs[32][64];

    float acc[25];
#pragma unroll
    for (int j = 0; j < 25; ++j) acc[j] = 0.f;

    const float* __restrict__ xb = x + (size_t)b * CC * NN;

    for (int c0 = 0; c0 < CC; c0 += 32) {
        // stage 32 rows x 64 cols (cols 49..63 zero-padded)
#pragma unroll
        for (int i = 0; i < 8; ++i) {
            const int row = (t >> 6) + i * 4;
            const int col = t & 63;
            float v = 0.f;
            if (col < 49) v = xb[(size_t)(c0 + row) * NN + nbase + col];
            xs[row][col] = v;
        }
        __syncthreads();

#pragma unroll
        for (int c = 0; c < 32; c += 4) {
            const float xv0 = xs[c + 0][tp];
            const float xv1 = xs[c + 1][tp];
            const float xv2 = xs[c + 2][tp];
            const float xv3 = xs[c + 3][tp];
#pragma unroll
            for (int j = 0; j < 25; ++j) {
                // uniform address -> s_load_dwordx4 (w in SGPRs)
                const float4 w4 = *reinterpret_cast<const float4*>(
                    wb + (size_t)j * CC + (c0 + c));
                float a = acc[j];
                a = fmaf(xv0, w4.x, a);
                a = fmaf(xv1, w4.y, a);
                a = fmaf(xv2, w4.z, a);
                a = fmaf(xv3, w4.w, a);
                acc[j] = a;
            }
        }
        __syncthreads();
    }

    if (tp < 49) {
        const int n = nbase + tp;
        float* __restrict__ so = scores + ((size_t)(b * NN + n)) * KK + kbase;
#pragma unroll
        for (int j = 0; j < 25; ++j) so[j] = acc[j];
    }
}

// ---------------------------------------------------------------------------
// Kernel B: per batch (grid=64, block=256):
//   per position: m = max_k(score+bias), amax, sumexp -> max_val = 1/sumexp
//   block reduce: ss = sum mv^2, s1 = sum mv
//   norm = mv / max(sqrt(ss), eps); histogram p_r (LDS atomics), L1 normalize
// ---------------------------------------------------------------------------
__global__ __launch_bounds__(256) void stats_kernel(
    const float* __restrict__ scores, const float* __restrict__ bias,
    const int* __restrict__ flagp,
    float* __restrict__ normArr, float* __restrict__ pr_out)
{
    const int b = blockIdx.x;
    const int t = threadIdx.x;

    __shared__ float bb[KK];
    __shared__ float hist[KK];
    __shared__ float red[8];
    __shared__ float bcast[2];

    if (t < KK) { bb[t] = bias[t]; hist[t] = 0.f; }
    __syncthreads();

    float mv = 0.f;
    int amax = 0;
    if (t < NN) {
        const float* __restrict__ srow = scores + ((size_t)(b * NN + t)) * KK;
        float m = -1e30f;
        int ai = 0;
#pragma unroll 4
        for (int k = 0; k < KK; k += 4) {
            const float4 s4 = *reinterpret_cast<const float4*>(srow + k);
            const float s0 = s4.x + bb[k + 0];
            const float s1 = s4.y + bb[k + 1];
            const float s2 = s4.z + bb[k + 2];
            const float s3 = s4.w + bb[k + 3];
            if (s0 > m) { m = s0; ai = k + 0; }
            if (s1 > m) { m = s1; ai = k + 1; }
            if (s2 > m) { m = s2; ai = k + 2; }
            if (s3 > m) { m = s3; ai = k + 3; }
        }
        float se = 0.f;
#pragma unroll 4
        for (int k = 0; k < KK; k += 4) {
            const float4 s4 = *reinterpret_cast<const float4*>(srow + k);
            se += expf(s4.x + bb[k + 0] - m);
            se += expf(s4.y + bb[k + 1] - m);
            se += expf(s4.z + bb[k + 2] - m);
            se += expf(s4.w + bb[k + 3] - m);
        }
        mv = 1.f / se;   // max of softmax row
        amax = ai;
    }

    // block reduction of sum(mv^2) and sum(mv)
    float v2 = mv * mv;
    float v1 = mv;
#pragma unroll
    for (int o = 32; o > 0; o >>= 1) {
        v2 += __shfl_down(v2, o);
        v1 += __shfl_down(v1, o);
    }
    const int wid = t >> 6;
    if ((t & 63) == 0) { red[wid] = v2; red[4 + wid] = v1; }
    __syncthreads();
    if (t == 0) {
        const float ss = red[0] + red[1] + red[2] + red[3];
        const float s1 = red[4] + red[5] + red[6] + red[7];
        const float scale = 1.f / fmaxf(sqrtf(ss), EPSF);
        bcast[0] = scale;
        bcast[1] = s1 * scale;   // row sum of histogram (all entries >= 0)
    }
    __syncthreads();

    const float scale = bcast[0];
    const int flag = *flagp;
    const float normv = mv * scale;
    if (t < NN) {
        normArr[b * NN + t] = normv;
        if (flag) atomicAdd(&hist[amax], normv);
    }
    __syncthreads();

    if (t < KK) {
        float pv = 0.f;
        if (flag) pv = hist[t] / fmaxf(bcast[1], EPSF);
        pr_out[(size_t)b * KK + t] = pv;
    }
}

// ---------------------------------------------------------------------------
// Kernel C: out[b,c,n] = x[b,c,n] * (1 + norm[b,n])   (residual fused)
// ---------------------------------------------------------------------------
__global__ __launch_bounds__(256) void scale_kernel(
    const float* __restrict__ x, const float* __restrict__ normArr,
    float* __restrict__ out)
{
    const unsigned total4 = (unsigned)(BB * CC * NN) / 4u;
    unsigned i = blockIdx.x * blockDim.x + threadIdx.x;
    const unsigned stride = gridDim.x * blockDim.x;
    for (; i < total4; i += stride) {
        const unsigned gi = i * 4u;
        const float4 xv = reinterpret_cast<const float4*>(x)[i];
        float vals[4] = {xv.x, xv.y, xv.z, xv.w};
#pragma unroll
        for (int j = 0; j < 4; ++j) {
            const unsigned g = gi + j;
            const unsigned n  = g % (unsigned)NN;
            const unsigned bi = g / (unsigned)(CC * NN);
            const float nv = normArr[bi * NN + n];
            vals[j] = vals[j] * (1.f + nv);
        }
        const float4 ov = {vals[0], vals[1], vals[2], vals[3]};
        reinterpret_cast<float4*>(out)[i] = ov;
    }
}

// ---------------------------------------------------------------------------
extern "C" void kernel_launch(void* const* d_in, const int* in_sizes, int n_in,
                              void* d_out, int out_size, void* d_ws, size_t ws_size,
                              hipStream_t stream)
{
    const float* x    = (const float*)d_in[0];
    const float* fc_w = (const float*)d_in[1];
    const float* fc_b = (const float*)d_in[2];
    const int*   flag = (const int*)d_in[3];

    float* out = (float*)d_out;
    float* pr  = out + (size_t)BB * CC * NN;       // p_r appended after out

    float* scores  = (float*)d_ws;                  // [B][N][K] = 10.04 MB
    float* normArr = scores + (size_t)BB * NN * KK; // [B][N]    = 50 KB

    scores_kernel<<<512, 256, 0, stream>>>(x, fc_w, scores);
    stats_kernel<<<64, 256, 0, stream>>>(scores, fc_b, flag, normArr, pr);
    scale_kernel<<<2048, 256, 0, stream>>>(x, normArr, out);
}

// Round 3
// 822.294 us; speedup vs baseline: 1.0782x; 1.0782x over previous
//
#include <hip/hip_runtime.h>

#define BB   64
#define CC   2208
#define NN   196
#define KK   200
#define MM   (BB * NN)      // 12544 = 196 * 64
#define BK   32
#define NCH  (CC / BK)      // 69
#define EPSF 1e-12f

// ---------------------------------------------------------------------------
// Kernel A: scores[m][k] = sum_c x[b(m), c, n(m)] * w[k][c]
// Flat M = 12544 positions. Tiles: BM=64 (196 tiles exact), BN=64 (classes
// padded 200->256, 4 tiles), BK=32. Block 256 = 16x16 threads, 4x4 acc each.
// Both operands staged in LDS; reg-prefetch of next chunk hides mem latency.
// ---------------------------------------------------------------------------
__global__ __launch_bounds__(256) void scores_kernel(
    const float* __restrict__ x, const float* __restrict__ w,
    float* __restrict__ scores)
{
    // XCD-aware swizzle: 784 blocks = 8 XCDs x 98 (bijective)
    const int raw = blockIdx.x;
    const int wg  = (raw & 7) * 98 + (raw >> 3);
    const int tm  = wg >> 2;            // m-tile 0..195
    const int ck  = wg & 3;             // class tile 0..3
    const int kbase = ck * 64;
    const int m0    = tm * 64;

    const int t  = threadIdx.x;
    const int tx = t & 15;              // class quad 0..15
    const int ty = t >> 4;              // pos quad 0..15

    __shared__ float xs[BK][64];
    __shared__ float ws[BK][64];

    // --- staging maps (computed once) ---
    // x: thread stages column scol (one m), rows srow+4i, i=0..7
    const int scol = t & 63;
    const int srow = t >> 6;
    const int m_s  = m0 + scol;
    const int b_s  = m_s / NN;
    const int n_s  = m_s - b_s * NN;
    const float* __restrict__ xsrc = x + (size_t)b_s * CC * NN + n_s;

    // w: thread stages class-row kl, c-quads cq*4 + 16i, i=0..1
    const int kl = t >> 2;              // 0..63
    const int cq = t & 3;               // 0..3
    const bool wvalid = (kbase + kl) < KK;
    const float* __restrict__ wsrc = w + (size_t)(kbase + kl) * CC + cq * 4;

    float  xr[8];
    float4 wr[2];
    const float4 z4 = {0.f, 0.f, 0.f, 0.f};

    // prologue: fetch chunk 0 into regs, write LDS
#pragma unroll
    for (int i = 0; i < 8; ++i)
        xr[i] = xsrc[(size_t)(srow + 4 * i) * NN];
#pragma unroll
    for (int i = 0; i < 2; ++i)
        wr[i] = wvalid ? *(const float4*)(wsrc + 16 * i) : z4;

#pragma unroll
    for (int i = 0; i < 8; ++i) xs[srow + 4 * i][scol] = xr[i];
#pragma unroll
    for (int i = 0; i < 2; ++i) {
        const int c = cq * 4 + 16 * i;
        ws[c + 0][kl] = wr[i].x;
        ws[c + 1][kl] = wr[i].y;
        ws[c + 2][kl] = wr[i].z;
        ws[c + 3][kl] = wr[i].w;
    }

    float acc[4][4];
#pragma unroll
    for (int i = 0; i < 4; ++i)
#pragma unroll
        for (int j = 0; j < 4; ++j) acc[i][j] = 0.f;

    for (int ci = 0; ci < NCH; ++ci) {
        __syncthreads();   // LDS writes of chunk ci visible

        // prefetch chunk ci+1 into regs (latency hidden under inner loop)
        const int c0n = (ci + 1) * BK;
        if (ci + 1 < NCH) {
#pragma unroll
            for (int i = 0; i < 8; ++i)
                xr[i] = xsrc[(size_t)(c0n + srow + 4 * i) * NN];
#pragma unroll
            for (int i = 0; i < 2; ++i)
                wr[i] = wvalid ? *(const float4*)(wsrc + c0n + 16 * i) : z4;
        }

        // inner: 32 c-steps x (2 ds_read_b128 + 16 FMA)
#pragma unroll
        for (int c = 0; c < BK; ++c) {
            const float4 xa = *(const float4*)&xs[c][ty * 4];
            const float4 wb = *(const float4*)&ws[c][tx * 4];
            acc[0][0] = fmaf(xa.x, wb.x, acc[0][0]);
            acc[0][1] = fmaf(xa.x, wb.y, acc[0][1]);
            acc[0][2] = fmaf(xa.x, wb.z, acc[0][2]);
            acc[0][3] = fmaf(xa.x, wb.w, acc[0][3]);
            acc[1][0] = fmaf(xa.y, wb.x, acc[1][0]);
            acc[1][1] = fmaf(xa.y, wb.y, acc[1][1]);
            acc[1][2] = fmaf(xa.y, wb.z, acc[1][2]);
            acc[1][3] = fmaf(xa.y, wb.w, acc[1][3]);
            acc[2][0] = fmaf(xa.z, wb.x, acc[2][0]);
            acc[2][1] = fmaf(xa.z, wb.y, acc[2][1]);
            acc[2][2] = fmaf(xa.z, wb.z, acc[2][2]);
            acc[2][3] = fmaf(xa.z, wb.w, acc[2][3]);
            acc[3][0] = fmaf(xa.w, wb.x, acc[3][0]);
            acc[3][1] = fmaf(xa.w, wb.y, acc[3][1]);
            acc[3][2] = fmaf(xa.w, wb.z, acc[3][2]);
            acc[3][3] = fmaf(xa.w, wb.w, acc[3][3]);
        }

        __syncthreads();   // all reads of chunk ci done

        if (ci + 1 < NCH) {
#pragma unroll
            for (int i = 0; i < 8; ++i) xs[srow + 4 * i][scol] = xr[i];
#pragma unroll
            for (int i = 0; i < 2; ++i) {
                const int c = cq * 4 + 16 * i;
                ws[c + 0][kl] = wr[i].x;
                ws[c + 1][kl] = wr[i].y;
                ws[c + 2][kl] = wr[i].z;
                ws[c + 3][kl] = wr[i].w;
            }
        }
    }

    // write-out: 4 rows x float4 of classes (200 % 4 == 0 -> all-or-nothing)
    if (kbase + tx * 4 < KK) {
#pragma unroll
        for (int i = 0; i < 4; ++i) {
            const float4 o = {acc[i][0], acc[i][1], acc[i][2], acc[i][3]};
            *(float4*)&scores[(size_t)(m0 + ty * 4 + i) * KK + kbase + tx * 4] = o;
        }
    }
}

// ---------------------------------------------------------------------------
// Kernel B: per batch: max/argmax/sumexp -> max_val; L2 norm; histogram; L1
// ---------------------------------------------------------------------------
__global__ __launch_bounds__(256) void stats_kernel(
    const float* __restrict__ scores, const float* __restrict__ bias,
    const int* __restrict__ flagp,
    float* __restrict__ normArr, float* __restrict__ pr_out)
{
    const int b = blockIdx.x;
    const int t = threadIdx.x;

    __shared__ float bb[KK];
    __shared__ float hist[KK];
    __shared__ float red[8];
    __shared__ float bcast[2];

    if (t < KK) { bb[t] = bias[t]; hist[t] = 0.f; }
    __syncthreads();

    float mv = 0.f;
    int amax = 0;
    if (t < NN) {
        const float* __restrict__ srow = scores + ((size_t)(b * NN + t)) * KK;
        float m = -1e30f;
        int ai = 0;
#pragma unroll 4
        for (int k = 0; k < KK; k += 4) {
            const float4 s4 = *reinterpret_cast<const float4*>(srow + k);
            const float s0 = s4.x + bb[k + 0];
            const float s1 = s4.y + bb[k + 1];
            const float s2 = s4.z + bb[k + 2];
            const float s3 = s4.w + bb[k + 3];
            if (s0 > m) { m = s0; ai = k + 0; }
            if (s1 > m) { m = s1; ai = k + 1; }
            if (s2 > m) { m = s2; ai = k + 2; }
            if (s3 > m) { m = s3; ai = k + 3; }
        }
        float se = 0.f;
#pragma unroll 4
        for (int k = 0; k < KK; k += 4) {
            const float4 s4 = *reinterpret_cast<const float4*>(srow + k);
            se += expf(s4.x + bb[k + 0] - m);
            se += expf(s4.y + bb[k + 1] - m);
            se += expf(s4.z + bb[k + 2] - m);
            se += expf(s4.w + bb[k + 3] - m);
        }
        mv = 1.f / se;   // max of softmax row
        amax = ai;
    }

    float v2 = mv * mv;
    float v1 = mv;
#pragma unroll
    for (int o = 32; o > 0; o >>= 1) {
        v2 += __shfl_down(v2, o);
        v1 += __shfl_down(v1, o);
    }
    const int wid = t >> 6;
    if ((t & 63) == 0) { red[wid] = v2; red[4 + wid] = v1; }
    __syncthreads();
    if (t == 0) {
        const float ss = red[0] + red[1] + red[2] + red[3];
        const float s1 = red[4] + red[5] + red[6] + red[7];
        const float scale = 1.f / fmaxf(sqrtf(ss), EPSF);
        bcast[0] = scale;
        bcast[1] = s1 * scale;
    }
    __syncthreads();

    const float scale = bcast[0];
    const int flag = *flagp;
    const float normv = mv * scale;
    if (t < NN) {
        normArr[b * NN + t] = normv;
        if (flag) atomicAdd(&hist[amax], normv);
    }
    __syncthreads();

    if (t < KK) {
        float pv = 0.f;
        if (flag) pv = hist[t] / fmaxf(bcast[1], EPSF);
        pr_out[(size_t)b * KK + t] = pv;
    }
}

// ---------------------------------------------------------------------------
// Kernel C: out[b,c,n] = x[b,c,n] * (1 + norm[b,n])
// float4 never crosses a row (196 = 49*4): one div by 49 + one by CC per f4.
// ---------------------------------------------------------------------------
__global__ __launch_bounds__(256) void scale_kernel(
    const float4* __restrict__ x4, const float4* __restrict__ norm4,
    float4* __restrict__ out4)
{
    const unsigned total4 = (unsigned)(BB * CC * NN) / 4u;   // 6,924,288
    const unsigned R4 = NN / 4u;                             // 49
    unsigned i = blockIdx.x * 256u + threadIdx.x;
    const unsigned stride = gridDim.x * 256u;
    for (; i < total4; i += stride) {
        const unsigned r  = i / R4;          // row = b*CC + c
        const unsigned nq = i - r * R4;      // float4 index within row
        const unsigned b  = r / (unsigned)CC;
        const float4 nv = norm4[b * R4 + nq];
        const float4 xv = x4[i];
        float4 ov;
        ov.x = xv.x * (1.f + nv.x);
        ov.y = xv.y * (1.f + nv.y);
        ov.z = xv.z * (1.f + nv.z);
        ov.w = xv.w * (1.f + nv.w);
        out4[i] = ov;
    }
}

// ---------------------------------------------------------------------------
extern "C" void kernel_launch(void* const* d_in, const int* in_sizes, int n_in,
                              void* d_out, int out_size, void* d_ws, size_t ws_size,
                              hipStream_t stream)
{
    const float* x    = (const float*)d_in[0];
    const float* fc_w = (const float*)d_in[1];
    const float* fc_b = (const float*)d_in[2];
    const int*   flag = (const int*)d_in[3];

    float* out = (float*)d_out;
    float* pr  = out + (size_t)BB * CC * NN;        // p_r appended after out

    float* scores  = (float*)d_ws;                   // [M][K] = 10.04 MB
    float* normArr = scores + (size_t)MM * KK;       // [B][N] = 50 KB

    scores_kernel<<<784, 256, 0, stream>>>(x, fc_w, scores);
    stats_kernel<<<64, 256, 0, stream>>>(scores, fc_b, flag, normArr, pr);
    scale_kernel<<<2048, 256, 0, stream>>>(
        (const float4*)x, (const float4*)normArr, (float4*)out);
}

// Round 4
// 376.841 us; speedup vs baseline: 2.3528x; 2.1821x over previous
//
#include <hip/hip_runtime.h>

#define BB   64
#define CC   2208
#define NN   196
#define KK   200
#define MM   (BB * NN)     // 12544
#define KP   256           // classes padded
#define CP   2240          // channels padded (35*64)
#define NCH  35            // 64-channel chunks
#define EPSF 1e-12f

typedef __attribute__((ext_vector_type(8))) short  bf16x8;
typedef __attribute__((ext_vector_type(4))) float  f32x4;
typedef __attribute__((ext_vector_type(4))) unsigned int uint4v;
typedef __attribute__((ext_vector_type(2))) unsigned int uint2v;

// ---------------------------------------------------------------------------
// Kernel 0: split w into truncation hi/lo bf16, pad classes->256, ch->2240.
// Layout wh/wl[256][2240] ushort (bf16 bits).
// ---------------------------------------------------------------------------
__global__ __launch_bounds__(256) void wconv_kernel(
    const float* __restrict__ w, ushort* __restrict__ wh, ushort* __restrict__ wl)
{
    const int idx = (blockIdx.x * 256 + threadIdx.x) * 4;   // 4 channels/thread
    if (idx >= KP * CP) return;
    const int cl = idx / CP;
    const int ch = idx - cl * CP;
    unsigned hp[2], lp[2];
#pragma unroll
    for (int p = 0; p < 2; ++p) {
        unsigned hw[2], lw[2];
#pragma unroll
        for (int e = 0; e < 2; ++e) {
            const int c = ch + p * 2 + e;
            const float v = (cl < KK && c < CC) ? w[cl * CC + c] : 0.f;
            const unsigned b  = __float_as_uint(v);
            const unsigned hb = b & 0xFFFF0000u;
            const float    lf = v - __uint_as_float(hb);
            hw[e] = hb >> 16;
            lw[e] = __float_as_uint(lf) >> 16;
        }
        hp[p] = hw[0] | (hw[1] << 16);
        lp[p] = lw[0] | (lw[1] << 16);
    }
    *(uint2v*)&wh[idx] = uint2v{hp[0], hp[1]};
    *(uint2v*)&wl[idx] = uint2v{lp[0], lp[1]};
}

// ---------------------------------------------------------------------------
// Kernel 1: scores[m][k] (stride 256) = sum_c x[b(m),c,n(m)] * w[k][c]
// bf16 hi/lo 3-pass MFMA. 1 wave/block, wave tile 64x64 (4x4 fragments of
// 16x16x32). 784 blocks = 196 m-tiles x 4 class-tiles, kt-major (x streamed
// once per phase, L3 serves re-reads). No barriers (single wave).
// LDS [64][64] bf16 tiles, 128B rows, 16B-slot XOR swizzle (slot ^= row&7).
// ---------------------------------------------------------------------------
__global__ __launch_bounds__(64) void scores_kernel(
    const float* __restrict__ x, const ushort* __restrict__ wh,
    const ushort* __restrict__ wl, float* __restrict__ scoresP)
{
    const int bid = blockIdx.x;
    const int tm  = bid % 196;            // m-tile
    const int kt  = bid / 196;            // class tile (phase-major)
    const int m0  = tm * 64;
    const int kbase = kt * 64;
    const int t   = threadIdx.x;          // 0..63

    __shared__ __align__(16) ushort lds[4 * 64 * 64];   // 32 KB
    ushort* const xs_h = lds;
    ushort* const xs_l = lds + 4096;
    ushort* const ws_h = lds + 8192;
    ushort* const ws_l = lds + 12288;

    // x source: thread t owns m = m0 + t
    const int m   = m0 + t;
    const int b_s = m / NN;
    const int n_s = m - b_s * NN;
    const float* __restrict__ xsrc = x + b_s * CC * NN + n_s;   // + c*NN

    // w source: per load i: class row (t>>3)+8i, 16B chunk (t&7)
    const int wrow0 = kbase + (t >> 3);
    const int wcol0 = (t & 7) * 8;

    const int lr = t & 15;       // fragment lane row/col
    const int kg = t >> 4;       // k-group 0..3

    f32x4 acc[4][4];
#pragma unroll
    for (int i = 0; i < 4; ++i)
#pragma unroll
        for (int j = 0; j < 4; ++j) acc[i][j] = f32x4{0.f, 0.f, 0.f, 0.f};

    for (int ci = 0; ci < NCH; ++ci) {
        const int c0 = ci * 64;

        // ---- stage x: 64 channels for this thread's m; convert to hi/lo ----
        for (int s = 0; s < 8; ++s) {
            const int cb = c0 + s * 8;
            float v[8];
            if (cb + 7 < CC) {
#pragma unroll
                for (int e = 0; e < 8; ++e) v[e] = xsrc[(cb + e) * NN];
            } else {
#pragma unroll
                for (int e = 0; e < 8; ++e)
                    v[e] = (cb + e < CC) ? xsrc[(cb + e) * NN] : 0.f;
            }
            unsigned hpk[4], lpk[4];
#pragma unroll
            for (int p = 0; p < 4; ++p) {
                const unsigned b0 = __float_as_uint(v[2 * p]);
                const unsigned b1 = __float_as_uint(v[2 * p + 1]);
                const unsigned h0 = b0 & 0xFFFF0000u;
                const unsigned h1 = b1 & 0xFFFF0000u;
                const float l0 = v[2 * p]     - __uint_as_float(h0);
                const float l1 = v[2 * p + 1] - __uint_as_float(h1);
                hpk[p] = (h0 >> 16) | h1;
                lpk[p] = (__float_as_uint(l0) >> 16) |
                         (__float_as_uint(l1) & 0xFFFF0000u);
            }
            const int sl = (s ^ (t & 7)) * 8;
            *(uint4v*)&xs_h[t * 64 + sl] = uint4v{hpk[0], hpk[1], hpk[2], hpk[3]};
            *(uint4v*)&xs_l[t * 64 + sl] = uint4v{lpk[0], lpk[1], lpk[2], lpk[3]};
        }

        // ---- stage w: 64 classes x 64 channels (already bf16) ----
#pragma unroll
        for (int i = 0; i < 8; ++i) {
            const int cl  = (t >> 3) + 8 * i;
            const int off = (wrow0 + 8 * i) * CP + c0 + wcol0;
            const uint4v hv = *(const uint4v*)&wh[off];
            const uint4v lv = *(const uint4v*)&wl[off];
            const int sl = ((t & 7) ^ (cl & 7)) * 8;
            *(uint4v*)&ws_h[cl * 64 + sl] = hv;
            *(uint4v*)&ws_l[cl * 64 + sl] = lv;
        }

        // ---- compute: 2 K-steps of 32 channels ----
#pragma unroll
        for (int ks = 0; ks < 2; ++ks) {
            bf16x8 Ah[4], Al[4], Bh[4], Bl[4];
#pragma unroll
            for (int f = 0; f < 4; ++f) {
                const int r  = f * 16 + lr;
                const int o  = r * 64 + (((ks * 4 + kg) ^ (r & 7)) * 8);
                Ah[f] = *(const bf16x8*)&xs_h[o];
                Al[f] = *(const bf16x8*)&xs_l[o];
                Bh[f] = *(const bf16x8*)&ws_h[o];
                Bl[f] = *(const bf16x8*)&ws_l[o];
            }
#pragma unroll
            for (int mf = 0; mf < 4; ++mf)
#pragma unroll
                for (int kf = 0; kf < 4; ++kf) {
                    acc[mf][kf] = __builtin_amdgcn_mfma_f32_16x16x32_bf16(
                        Ah[mf], Bh[kf], acc[mf][kf], 0, 0, 0);
                    acc[mf][kf] = __builtin_amdgcn_mfma_f32_16x16x32_bf16(
                        Al[mf], Bh[kf], acc[mf][kf], 0, 0, 0);
                    acc[mf][kf] = __builtin_amdgcn_mfma_f32_16x16x32_bf16(
                        Ah[mf], Bl[kf], acc[mf][kf], 0, 0, 0);
                }
        }
    }

    // ---- epilogue: C/D layout col=lane&15, row=(lane>>4)*4+reg ----
    const int orow = (t >> 4) * 4;
    const int ocol = t & 15;
#pragma unroll
    for (int mf = 0; mf < 4; ++mf)
#pragma unroll
        for (int kf = 0; kf < 4; ++kf)
#pragma unroll
            for (int r = 0; r < 4; ++r)
                scoresP[(m0 + mf * 16 + orow + r) * KP + kbase + kf * 16 + ocol] =
                    acc[mf][kf][r];
}

// ---------------------------------------------------------------------------
// Kernel 2: per batch: max/argmax/sumexp -> max_val; L2 norm; hist; L1 norm
// ---------------------------------------------------------------------------
__global__ __launch_bounds__(256) void stats_kernel(
    const float* __restrict__ scoresP, const float* __restrict__ bias,
    const int* __restrict__ flagp,
    float* __restrict__ normArr, float* __restrict__ pr_out)
{
    const int b = blockIdx.x;
    const int t = threadIdx.x;

    __shared__ float bb[KK];
    __shared__ float hist[KK];
    __shared__ float red[8];
    __shared__ float bcast[2];

    if (t < KK) { bb[t] = bias[t]; hist[t] = 0.f; }
    __syncthreads();

    float mv = 0.f;
    int amax = 0;
    if (t < NN) {
        const float* __restrict__ srow = scoresP + (b * NN + t) * KP;
        float m = -1e30f;
        int ai = 0;
#pragma unroll 4
        for (int k = 0; k < KK; k += 4) {
            const float4 s4 = *reinterpret_cast<const float4*>(srow + k);
            const float s0 = s4.x + bb[k + 0];
            const float s1 = s4.y + bb[k + 1];
            const float s2 = s4.z + bb[k + 2];
            const float s3 = s4.w + bb[k + 3];
            if (s0 > m) { m = s0; ai = k + 0; }
            if (s1 > m) { m = s1; ai = k + 1; }
            if (s2 > m) { m = s2; ai = k + 2; }
            if (s3 > m) { m = s3; ai = k + 3; }
        }
        float se = 0.f;
#pragma unroll 4
        for (int k = 0; k < KK; k += 4) {
            const float4 s4 = *reinterpret_cast<const float4*>(srow + k);
            se += expf(s4.x + bb[k + 0] - m);
            se += expf(s4.y + bb[k + 1] - m);
            se += expf(s4.z + bb[k + 2] - m);
            se += expf(s4.w + bb[k + 3] - m);
        }
        mv = 1.f / se;   // max of softmax row
        amax = ai;
    }

    float v2 = mv * mv;
    float v1 = mv;
#pragma unroll
    for (int o = 32; o > 0; o >>= 1) {
        v2 += __shfl_down(v2, o);
        v1 += __shfl_down(v1, o);
    }
    const int wid = t >> 6;
    if ((t & 63) == 0) { red[wid] = v2; red[4 + wid] = v1; }
    __syncthreads();
    if (t == 0) {
        const float ss = red[0] + red[1] + red[2] + red[3];
        const float s1 = red[4] + red[5] + red[6] + red[7];
        const float scale = 1.f / fmaxf(sqrtf(ss), EPSF);
        bcast[0] = scale;
        bcast[1] = s1 * scale;
    }
    __syncthreads();

    const float scale = bcast[0];
    const int flag = *flagp;
    const float normv = mv * scale;
    if (t < NN) {
        normArr[b * NN + t] = normv;
        if (flag) atomicAdd(&hist[amax], normv);
    }
    __syncthreads();

    if (t < KK) {
        float pv = 0.f;
        if (flag) pv = hist[t] / fmaxf(bcast[1], EPSF);
        pr_out[b * KK + t] = pv;
    }
}

// ---------------------------------------------------------------------------
// Kernel 3: out[b,c,n] = x[b,c,n] * (1 + norm[b,n])
// ---------------------------------------------------------------------------
__global__ __launch_bounds__(256) void scale_kernel(
    const float4* __restrict__ x4, const float4* __restrict__ norm4,
    float4* __restrict__ out4)
{
    const unsigned total4 = (unsigned)(BB * CC * NN) / 4u;
    const unsigned R4 = NN / 4u;                             // 49
    unsigned i = blockIdx.x * 256u + threadIdx.x;
    const unsigned stride = gridDim.x * 256u;
    for (; i < total4; i += stride) {
        const unsigned r  = i / R4;
        const unsigned nq = i - r * R4;
        const unsigned b  = r / (unsigned)CC;
        const float4 nv = norm4[b * R4 + nq];
        const float4 xv = x4[i];
        float4 ov;
        ov.x = xv.x * (1.f + nv.x);
        ov.y = xv.y * (1.f + nv.y);
        ov.z = xv.z * (1.f + nv.z);
        ov.w = xv.w * (1.f + nv.w);
        out4[i] = ov;
    }
}

// ---------------------------------------------------------------------------
extern "C" void kernel_launch(void* const* d_in, const int* in_sizes, int n_in,
                              void* d_out, int out_size, void* d_ws, size_t ws_size,
                              hipStream_t stream)
{
    const float* x    = (const float*)d_in[0];
    const float* fc_w = (const float*)d_in[1];
    const float* fc_b = (const float*)d_in[2];
    const int*   flag = (const int*)d_in[3];

    float* out = (float*)d_out;
    float* pr  = out + (size_t)BB * CC * NN;            // p_r appended

    char* wsb = (char*)d_ws;
    float*  scoresP = (float*)wsb;                       // [MM][KP] 12.85 MB
    float*  normArr = (float*)(wsb + (size_t)MM * KP * 4);          // 50 KB
    ushort* wh      = (ushort*)(wsb + (size_t)MM * KP * 4 + MM * 4);
    ushort* wl      = wh + (size_t)KP * CP;              // 1.15 MB each

    wconv_kernel<<<560, 256, 0, stream>>>(fc_w, wh, wl);
    scores_kernel<<<784, 64, 0, stream>>>(x, wh, wl, scoresP);
    stats_kernel<<<64, 256, 0, stream>>>(scoresP, fc_b, flag, normArr, pr);
    scale_kernel<<<2048, 256, 0, stream>>>(
        (const float4*)x, (const float4*)normArr, (float4*)out);
}

// Round 6
// 261.612 us; speedup vs baseline: 3.3891x; 1.4405x over previous
//
#include <hip/hip_runtime.h>

#define BB   64
#define CC   2208
#define NN   196
#define KK   200
#define MM   (BB * NN)     // 12544
#define KP   256           // classes padded
#define CP   2240          // channels padded (35*64)
#define NCH  35            // 64-channel chunks
#define CSPL 18            // chunks in c-split 0 (split 1 gets 17)
#define EPSF 1e-12f

typedef __attribute__((ext_vector_type(8))) short  bf16x8;
typedef __attribute__((ext_vector_type(4))) float  f32x4;
typedef __attribute__((ext_vector_type(4))) unsigned int uint4v;
typedef __attribute__((ext_vector_type(2))) unsigned int uint2v;

// ---------------------------------------------------------------------------
// Kernel 0: split w into truncation hi/lo bf16, pad classes->256, ch->2240.
// ---------------------------------------------------------------------------
__global__ __launch_bounds__(256) void wconv_kernel(
    const float* __restrict__ w, ushort* __restrict__ wh, ushort* __restrict__ wl)
{
    const int idx = (blockIdx.x * 256 + threadIdx.x) * 4;
    if (idx >= KP * CP) return;
    const int cl = idx / CP;
    const int ch = idx - cl * CP;
    unsigned hp[2], lp[2];
#pragma unroll
    for (int p = 0; p < 2; ++p) {
        unsigned hw[2], lw[2];
#pragma unroll
        for (int e = 0; e < 2; ++e) {
            const int c = ch + p * 2 + e;
            const float v = (cl < KK && c < CC) ? w[cl * CC + c] : 0.f;
            const unsigned hb = __float_as_uint(v) & 0xFFFF0000u;
            const float    lf = v - __uint_as_float(hb);
            hw[e] = hb >> 16;
            lw[e] = __float_as_uint(lf) >> 16;
        }
        hp[p] = hw[0] | (hw[1] << 16);
        lp[p] = lw[0] | (lw[1] << 16);
    }
    *(uint2v*)&wh[idx] = uint2v{hp[0], hp[1]};
    *(uint2v*)&wl[idx] = uint2v{lp[0], lp[1]};
}

// ---------------------------------------------------------------------------
// Kernel 1: partial scores, bf16 hi/lo 3-pass MFMA.
// Block = 256 thr = 4 waves; wave wv owns class tile [wv*64, wv*64+64).
// x tile [64 m][64 c] staged once per block (shared); w per wave.
// Grid 392 = 196 m-tiles x 2 c-splits (cs0: ch 0..1151, cs1: 1152..2239),
// XCD-bijective swizzle (392 = 8*49). Partials to sp0/sp1 (stride KP).
// LDS granule swizzle: physical granule = g ^ (row&7), 16B granules.
// ---------------------------------------------------------------------------
__global__ __launch_bounds__(256, 2) void scores_kernel(
    const float* __restrict__ x, const ushort* __restrict__ wh,
    const ushort* __restrict__ wl, float* __restrict__ sp0,
    float* __restrict__ sp1)
{
    const int raw = blockIdx.x;
    const int sw  = (raw & 7) * 49 + (raw >> 3);
    const int cs  = sw / 196;
    const int tm  = sw - cs * 196;
    const int m0  = tm * 64;
    const int t   = threadIdx.x;
    const int wv  = t >> 6;            // wave id = class tile = x ch-quarter
    const int l   = t & 63;

    __shared__ __align__(16) ushort xs_h[64 * 64];
    __shared__ __align__(16) ushort xs_l[64 * 64];
    __shared__ __align__(16) ushort ws_h[4][64 * 64];
    __shared__ __align__(16) ushort ws_l[4][64 * 64];

    // x source: thread owns m = m0 + l
    const int m   = m0 + l;
    const int b_s = m / NN;
    const int n_s = m - b_s * NN;
    const float* __restrict__ xsrc = x + (size_t)b_s * CC * NN + n_s;

    const int kbase = wv * 64;
    const int lr = l & 15;
    const int kg = l >> 4;

    f32x4 acc[4][4];
#pragma unroll
    for (int i = 0; i < 4; ++i)
#pragma unroll
        for (int j = 0; j < 4; ++j) acc[i][j] = f32x4{0.f, 0.f, 0.f, 0.f};

    const int ci0 = cs ? CSPL : 0;
    const int ci1 = cs ? NCH : CSPL;

    for (int ci = ci0; ci < ci1; ++ci) {
        const int c0 = ci * 64;

        // ---- stage x (cooperative): 16 channels per thread, convert hi/lo --
        {
            const int cb = c0 + wv * 16;
            float v[16];
            if (cb + 15 < CC) {
#pragma unroll
                for (int e = 0; e < 16; ++e) v[e] = xsrc[(cb + e) * NN];
            } else {
#pragma unroll
                for (int e = 0; e < 16; ++e)
                    v[e] = (cb + e < CC) ? xsrc[(cb + e) * NN] : 0.f;
            }
            unsigned hpk[8], lpk[8];
#pragma unroll
            for (int p = 0; p < 8; ++p) {
                const unsigned b0 = __float_as_uint(v[2 * p]);
                const unsigned b1 = __float_as_uint(v[2 * p + 1]);
                const unsigned h0 = b0 & 0xFFFF0000u;
                const unsigned h1 = b1 & 0xFFFF0000u;
                const float l0 = v[2 * p]     - __uint_as_float(h0);
                const float l1 = v[2 * p + 1] - __uint_as_float(h1);
                hpk[p] = (h0 >> 16) | h1;
                lpk[p] = (__float_as_uint(l0) >> 16) |
                         (__float_as_uint(l1) & 0xFFFF0000u);
            }
#pragma unroll
            for (int i = 0; i < 2; ++i) {
                const int g   = wv * 2 + i;
                const int off = l * 64 + ((g ^ (l & 7)) * 8);
                *(uint4v*)&xs_h[off] =
                    uint4v{hpk[4 * i], hpk[4 * i + 1], hpk[4 * i + 2], hpk[4 * i + 3]};
                *(uint4v*)&xs_l[off] =
                    uint4v{lpk[4 * i], lpk[4 * i + 1], lpk[4 * i + 2], lpk[4 * i + 3]};
            }
        }

        // ---- stage w (per wave, own 64-class tile) ----
#pragma unroll
        for (int i = 0; i < 8; ++i) {
            const int cl = (l >> 3) + 8 * i;
            const size_t off = (size_t)(kbase + cl) * CP + c0 + (l & 7) * 8;
            const uint4v hv = *(const uint4v*)&wh[off];
            const uint4v lv = *(const uint4v*)&wl[off];
            const int so = cl * 64 + (((l & 7) ^ (cl & 7)) * 8);
            *(uint4v*)&ws_h[wv][so] = hv;
            *(uint4v*)&ws_l[wv][so] = lv;
        }

        __syncthreads();

        // ---- compute: 2 K-steps x (16 frag reads + 48 MFMA pass-major) ----
#pragma unroll
        for (int ks = 0; ks < 2; ++ks) {
            bf16x8 Ah[4], Al[4], Bh[4], Bl[4];
#pragma unroll
            for (int f = 0; f < 4; ++f) {
                const int r = f * 16 + lr;
                const int o = r * 64 + (((ks * 4 + kg) ^ (r & 7)) * 8);
                Ah[f] = *(const bf16x8*)&xs_h[o];
                Al[f] = *(const bf16x8*)&xs_l[o];
                Bh[f] = *(const bf16x8*)&ws_h[wv][o];
                Bl[f] = *(const bf16x8*)&ws_l[wv][o];
            }
            // pass 1: hi*hi (16 independent)
#pragma unroll
            for (int mf = 0; mf < 4; ++mf)
#pragma unroll
                for (int kf = 0; kf < 4; ++kf)
                    acc[mf][kf] = __builtin_amdgcn_mfma_f32_16x16x32_bf16(
                        Ah[mf], Bh[kf], acc[mf][kf], 0, 0, 0);
            // pass 2: lo*hi
#pragma unroll
            for (int mf = 0; mf < 4; ++mf)
#pragma unroll
                for (int kf = 0; kf < 4; ++kf)
                    acc[mf][kf] = __builtin_amdgcn_mfma_f32_16x16x32_bf16(
                        Al[mf], Bh[kf], acc[mf][kf], 0, 0, 0);
            // pass 3: hi*lo
#pragma unroll
            for (int mf = 0; mf < 4; ++mf)
#pragma unroll
                for (int kf = 0; kf < 4; ++kf)
                    acc[mf][kf] = __builtin_amdgcn_mfma_f32_16x16x32_bf16(
                        Ah[mf], Bl[kf], acc[mf][kf], 0, 0, 0);
        }

        __syncthreads();
    }

    // ---- epilogue: C/D layout col=lane&15, row=(lane>>4)*4+reg ----
    float* __restrict__ sp = cs ? sp1 : sp0;
    const int orow = (l >> 4) * 4;
    const int ocol = l & 15;
#pragma unroll
    for (int mf = 0; mf < 4; ++mf)
#pragma unroll
        for (int kf = 0; kf < 4; ++kf)
#pragma unroll
            for (int r = 0; r < 4; ++r)
                sp[(size_t)(m0 + mf * 16 + orow + r) * KP + kbase + kf * 16 + ocol] =
                    acc[mf][kf][r];
}

// ---------------------------------------------------------------------------
// Kernel 2a: per position (4 threads/row): online softmax over summed
// partials + bias -> mv = 1/sumexp (= softmax max), amax (first-max index).
// ---------------------------------------------------------------------------
__global__ __launch_bounds__(256) void stats_pos_kernel(
    const float* __restrict__ sp0, const float* __restrict__ sp1,
    const float* __restrict__ bias, float* __restrict__ mvArr,
    int* __restrict__ amaxArr)
{
    __shared__ float bb[KK];
    const int t = threadIdx.x;
    if (t < KK / 4) ((float4*)bb)[t] = ((const float4*)bias)[t];
    __syncthreads();

    const int p = blockIdx.x * 64 + (t >> 2);
    const int j = t & 3;
    const float* __restrict__ r0 = sp0 + (size_t)p * KP;
    const float* __restrict__ r1 = sp1 + (size_t)p * KP;

    float m = -1e30f, se = 0.f;
    int am = 0;
#pragma unroll
    for (int i = 0; i < 13; ++i) {
        const int k0 = i * 16 + j * 4;
        if (k0 < KK) {
            const float4 a4 = *(const float4*)(r0 + k0);
            const float4 b4 = *(const float4*)(r1 + k0);
            const float4 c4 = *(const float4*)(bb + k0);
            const float s[4] = {a4.x + b4.x + c4.x, a4.y + b4.y + c4.y,
                                a4.z + b4.z + c4.z, a4.w + b4.w + c4.w};
#pragma unroll
            for (int e = 0; e < 4; ++e) {
                const float sv = s[e];
                const float nm = fmaxf(m, sv);
                se = se * expf(m - nm) + expf(sv - nm);
                am = (sv > m) ? (k0 + e) : am;
                m = nm;
            }
        }
    }
    // combine the 4 threads of this position (adjacent lanes)
#pragma unroll
    for (int o = 1; o <= 2; o <<= 1) {
        const float m_o  = __shfl_xor(m, o);
        const float se_o = __shfl_xor(se, o);
        const int   am_o = __shfl_xor(am, o);
        const float nm = fmaxf(m, m_o);
        se = se * expf(m - nm) + se_o * expf(m_o - nm);
        am = (m_o > m || (m_o == m && am_o < am)) ? am_o : am;
        m = nm;
    }
    if (j == 0) { mvArr[p] = 1.f / se; amaxArr[p] = am; }
}

// ---------------------------------------------------------------------------
// Kernel 2b: per batch: L2 norm of mv, histogram of norm by amax, L1 norm.
// ---------------------------------------------------------------------------
__global__ __launch_bounds__(256) void stats_batch_kernel(
    const float* __restrict__ mvArr, const int* __restrict__ amaxArr,
    const int* __restrict__ flagp, float* __restrict__ normArr,
    float* __restrict__ pr_out)
{
    const int b = blockIdx.x;
    const int t = threadIdx.x;

    __shared__ float hist[KK];
    __shared__ float red[8];
    __shared__ float bcast[2];

    if (t < KK) hist[t] = 0.f;
    __syncthreads();

    float mv = 0.f;
    int am = 0;
    if (t < NN) { mv = mvArr[b * NN + t]; am = amaxArr[b * NN + t]; }

    float v2 = mv * mv;
    float v1 = mv;
#pragma unroll
    for (int o = 32; o > 0; o >>= 1) {
        v2 += __shfl_down(v2, o);
        v1 += __shfl_down(v1, o);
    }
    const int wid = t >> 6;
    if ((t & 63) == 0) { red[wid] = v2; red[4 + wid] = v1; }
    __syncthreads();
    if (t == 0) {
        const float ss = red[0] + red[1] + red[2] + red[3];
        const float s1 = red[4] + red[5] + red[6] + red[7];
        const float scale = 1.f / fmaxf(sqrtf(ss), EPSF);
        bcast[0] = scale;
        bcast[1] = s1 * scale;
    }
    __syncthreads();

    const float scale = bcast[0];
    const int flag = *flagp;
    const float normv = mv * scale;
    if (t < NN) {
        normArr[b * NN + t] = normv;
        if (flag) atomicAdd(&hist[am], normv);
    }
    __syncthreads();

    if (t < KK) {
        float pv = 0.f;
        if (flag) pv = hist[t] / fmaxf(bcast[1], EPSF);
        pr_out[(size_t)b * KK + t] = pv;
    }
}

// ---------------------------------------------------------------------------
// Kernel 3: out[b,c,n] = x[b,c,n] * (1 + norm[b,n])
// ---------------------------------------------------------------------------
__global__ __launch_bounds__(256) void scale_kernel(
    const float4* __restrict__ x4, const float4* __restrict__ norm4,
    float4* __restrict__ out4)
{
    const unsigned total4 = (unsigned)(BB * CC * NN) / 4u;
    const unsigned R4 = NN / 4u;                             // 49
    unsigned i = blockIdx.x * 256u + threadIdx.x;
    const unsigned stride = gridDim.x * 256u;
    for (; i < total4; i += stride) {
        const unsigned r  = i / R4;
        const unsigned nq = i - r * R4;
        const unsigned b  = r / (unsigned)CC;
        const float4 nv = norm4[b * R4 + nq];
        const float4 xv = x4[i];
        float4 ov;
        ov.x = xv.x * (1.f + nv.x);
        ov.y = xv.y * (1.f + nv.y);
        ov.z = xv.z * (1.f + nv.z);
        ov.w = xv.w * (1.f + nv.w);
        out4[i] = ov;
    }
}

// ---------------------------------------------------------------------------
extern "C" void kernel_launch(void* const* d_in, const int* in_sizes, int n_in,
                              void* d_out, int out_size, void* d_ws, size_t ws_size,
                              hipStream_t stream)
{
    const float* x    = (const float*)d_in[0];
    const float* fc_w = (const float*)d_in[1];
    const float* fc_b = (const float*)d_in[2];
    const int*   flag = (const int*)d_in[3];

    float* out = (float*)d_out;
    float* pr  = out + (size_t)BB * CC * NN;            // p_r appended

    char* wsb = (char*)d_ws;
    float*  sp0     = (float*)wsb;                       // 12.85 MB
    float*  sp1     = sp0 + (size_t)MM * KP;             // 12.85 MB
    float*  mvArr   = sp1 + (size_t)MM * KP;             // 50 KB
    int*    amaxArr = (int*)(mvArr + MM);                // 50 KB
    float*  normArr = (float*)(amaxArr + MM);            // 50 KB
    ushort* wh      = (ushort*)(normArr + MM);           // 1.15 MB
    ushort* wl      = wh + (size_t)KP * CP;              // 1.15 MB

    wconv_kernel<<<560, 256, 0, stream>>>(fc_w, wh, wl);
    scores_kernel<<<392, 256, 0, stream>>>(x, wh, wl, sp0, sp1);
    stats_pos_kernel<<<196, 256, 0, stream>>>(sp0, sp1, fc_b, mvArr, amaxArr);
    stats_batch_kernel<<<64, 256, 0, stream>>>(mvArr, amaxArr, flag, normArr, pr);
    scale_kernel<<<2048, 256, 0, stream>>>(
        (const float4*)x, (const float4*)normArr, (float4*)out);
}